// Round 1
// baseline (1359.317 us; speedup 1.0000x reference)
//
#include <hip/hip_runtime.h>

#define NHEADS 8
#define DKK    32
#define DVV    64
#define NTOK   1024
#define DIM    256

#define TI 32   // i rows per attn block
#define TJ 16   // j cols per chunk

// ---------------------------------------------------------------------------
// K1: q1/kk/vv = BN(conv1x1(x, W))  -> workspace, layout [b][chan][n]
// grid (128, 4), block 256.  Each block: 8 output channels, all 1024 positions.
// ---------------------------------------------------------------------------
__global__ __launch_bounds__(256) void qkv_kernel(
    const float* __restrict__ x,
    const float* __restrict__ Wq, const float* __restrict__ gq, const float* __restrict__ bq,
    const float* __restrict__ Wk, const float* __restrict__ gk, const float* __restrict__ bk,
    const float* __restrict__ Wv, const float* __restrict__ gv, const float* __restrict__ bv,
    float* __restrict__ q1, float* __restrict__ kk, float* __restrict__ vv)
{
    const int b   = blockIdx.y;
    const int o0  = blockIdx.x * 8;          // 0..1016
    const int tid = threadIdx.x;

    const float* W; const float* gg; const float* bb; float* outp;
    if (o0 < 256) {
        W = Wq + (size_t)o0 * DIM; gg = gq + o0; bb = bq + o0;
        outp = q1 + ((size_t)b * 256 + o0) * NTOK;
    } else if (o0 < 512) {
        int ol = o0 - 256;
        W = Wk + (size_t)ol * DIM; gg = gk + ol; bb = bk + ol;
        outp = kk + ((size_t)b * 256 + ol) * NTOK;
    } else {
        int ol = o0 - 512;
        W = Wv + (size_t)ol * DIM; gg = gv + ol; bb = bv + ol;
        outp = vv + ((size_t)b * 512 + ol) * NTOK;
    }

    const float* xb = x + (size_t)b * DIM * NTOK;
    float acc[8][4];
    #pragma unroll
    for (int o = 0; o < 8; ++o)
        #pragma unroll
        for (int r = 0; r < 4; ++r) acc[o][r] = 0.0f;

    for (int c = 0; c < DIM; ++c) {
        float xv[4];
        #pragma unroll
        for (int r = 0; r < 4; ++r) xv[r] = xb[(size_t)c * NTOK + r * 256 + tid];
        #pragma unroll
        for (int o = 0; o < 8; ++o) {
            float w = W[(size_t)o * DIM + c];
            #pragma unroll
            for (int r = 0; r < 4; ++r) acc[o][r] = fmaf(w, xv[r], acc[o][r]);
        }
    }
    #pragma unroll
    for (int o = 0; o < 8; ++o) {
        float g = gg[o], be = bb[o];
        #pragma unroll
        for (int r = 0; r < 4; ++r)
            outp[(size_t)o * NTOK + r * 256 + tid] = fmaf(g, acc[o][r], be);
    }
}

// ---------------------------------------------------------------------------
// K2: fused dual-branch attention with online softmax.
// grid (32, 8, 4) = (i-tile, head, batch), block 256.
// Writes gelu(out1|out2) in conv layout [b][1024 ch][n] to gbuf.
// ---------------------------------------------------------------------------
__global__ __launch_bounds__(256) void attn_kernel(
    const float* __restrict__ q1, const float* __restrict__ kk, const float* __restrict__ vv,
    const float* __restrict__ Wmk, const float* __restrict__ gmk, const float* __restrict__ bmk,
    const float* __restrict__ pos_emb, float* __restrict__ gbuf)
{
    __shared__ float q1s[TI][257];      // 32,896 B
    __shared__ float wmks[TJ][257];     // 16,448 B
    __shared__ float ks[TJ][33];        //  2,112 B
    __shared__ float vs[TJ][68];        //  4,352 B (rows 16B-aligned for float4)
    __shared__ float sd1[TI][17];       //  2,176 B
    __shared__ float sd2[TI][17];       //  2,176 B   total ~60.2 KB

    const int it  = blockIdx.x;
    const int h   = blockIdx.y;
    const int b   = blockIdx.z;
    const int i0  = it * TI;
    const int tid = threadIdx.x;

    // ---- load q1 tile: all 256 channels for 32 positions ----
    {
        const float* q1b = q1 + (size_t)b * 256 * NTOK;
        for (int e = tid; e < DIM * TI; e += 256) {
            int c = e >> 5, i = e & 31;
            q1s[i][c] = q1b[(size_t)c * NTOK + i0 + i];
        }
    }

    // phase-A identity
    const int jA   = tid & 15;
    const int isub = tid >> 4;           // 0..15 ; rows isub, isub+16
    // phase-B identity
    const int iB = tid >> 3;             // 0..31
    const int dg = tid & 7;              // owns d = dg*8 .. dg*8+7

    float acc1[8], acc2[8];
    #pragma unroll
    for (int u = 0; u < 8; ++u) { acc1[u] = 0.0f; acc2[u] = 0.0f; }
    float m1 = -INFINITY, l1 = 0.0f, m2 = -INFINITY, l2 = 0.0f;

    const float* wmkbase = Wmk + (size_t)h * NTOK * DIM;
    const float* kkb = kk + ((size_t)b * 256 + h * DKK) * NTOK;
    const float* vvb = vv + ((size_t)b * 512 + h * DVV) * NTOK;
    const float SCALE    = 0.17677669529663687f;   // 32^-0.5
    const float INVSCALE = 5.656854249492380f;     // sqrt(32)

    for (int jc = 0; jc < NTOK / TJ; ++jc) {
        const int j0 = jc * TJ;
        __syncthreads();   // previous phase-B readers done before restage

        // ---- stage Wmk rows, K tile, V tile ----
        for (int e = tid; e < TJ * DIM; e += 256) {
            int j = e >> 8, c = e & 255;
            wmks[j][c] = wmkbase[(size_t)(j0 + j) * DIM + c];
        }
        for (int e = tid; e < TJ * DKK; e += 256) {
            int d = e >> 4, j = e & 15;
            ks[j][d] = kkb[(size_t)d * NTOK + j0 + j];
        }
        for (int e = tid; e < TJ * DVV; e += 256) {
            int d = e >> 4, j = e & 15;
            vs[j][d] = vvb[(size_t)d * NTOK + j0 + j];
        }
        __syncthreads();

        // ---- phase A: logits for (2 rows) x (1 col) per thread ----
        {
            float d1a = 0.0f, d1b = 0.0f;
            for (int c = 0; c < DIM; ++c) {
                float w = wmks[jA][c];
                d1a = fmaf(w, q1s[isub][c],      d1a);
                d1b = fmaf(w, q1s[isub + 16][c], d1b);
            }
            float d2a = 0.0f, d2b = 0.0f;
            const int qb = h * DKK;
            #pragma unroll
            for (int dd = 0; dd < DKK; ++dd) {
                float kv = ks[jA][dd];
                d2a = fmaf(kv, q1s[isub][qb + dd],      d2a);
                d2b = fmaf(kv, q1s[isub + 16][qb + dd], d2b);
            }
            const int jg = j0 + jA;
            const int ch = h * NTOK + jg;
            const float gm = gmk[ch], bm = bmk[ch];
            const int jx = jg >> 5, jy = jg & 31;
            const int ia = i0 + isub, ib2 = ia + 16;
            int ax = (ia >> 5) - jx;  ax = ax < 0 ? -ax : ax;
            int ay = (ia & 31) - jy;  ay = ay < 0 ? -ay : ay;
            int bx = (ib2 >> 5) - jx; bx = bx < 0 ? -bx : bx;
            int by = (ib2 & 31) - jy; by = by < 0 ? -by : by;
            float biasa = pos_emb[(ax * 32 + ay) * NHEADS + h] * INVSCALE;
            float biasb = pos_emb[(bx * 32 + by) * NHEADS + h] * INVSCALE;
            sd1[isub][jA]      = fmaf(gm, d1a, bm) + biasa;
            sd1[isub + 16][jA] = fmaf(gm, d1b, bm) + biasb;
            sd2[isub][jA]      = d2a * SCALE;
            sd2[isub + 16][jA] = d2b * SCALE;
        }
        __syncthreads();

        // ---- phase B: online softmax + PV accumulate ----
        {
            // branch 1
            float cmax = -INFINITY;
            #pragma unroll
            for (int j = 0; j < TJ; ++j) cmax = fmaxf(cmax, sd1[iB][j]);
            float mnew = fmaxf(m1, cmax);
            float sc = __expf(m1 - mnew);
            l1 *= sc;
            #pragma unroll
            for (int u = 0; u < 8; ++u) acc1[u] *= sc;
            #pragma unroll
            for (int j = 0; j < TJ; ++j) {
                float p = __expf(sd1[iB][j] - mnew);
                l1 += p;
                #pragma unroll
                for (int u = 0; u < 8; ++u)
                    acc1[u] = fmaf(p, vs[j][dg * 8 + u], acc1[u]);
            }
            m1 = mnew;
            // branch 2
            cmax = -INFINITY;
            #pragma unroll
            for (int j = 0; j < TJ; ++j) cmax = fmaxf(cmax, sd2[iB][j]);
            mnew = fmaxf(m2, cmax);
            sc = __expf(m2 - mnew);
            l2 *= sc;
            #pragma unroll
            for (int u = 0; u < 8; ++u) acc2[u] *= sc;
            #pragma unroll
            for (int j = 0; j < TJ; ++j) {
                float p = __expf(sd2[iB][j] - mnew);
                l2 += p;
                #pragma unroll
                for (int u = 0; u < 8; ++u)
                    acc2[u] = fmaf(p, vs[j][dg * 8 + u], acc2[u]);
            }
            m2 = mnew;
        }
    }

    // ---- epilogue: normalize, GELU, store concat conv layout ----
    {
        const float inv1 = 1.0f / l1, inv2 = 1.0f / l2;
        const int ig = i0 + iB;
        float* gb = gbuf + (size_t)b * 1024 * NTOK;
        #pragma unroll
        for (int u = 0; u < 8; ++u) {
            int d = dg * 8 + u;
            float o1 = acc1[u] * inv1;
            float o2 = acc2[u] * inv2;
            o1 = 0.5f * o1 * (1.0f + erff(o1 * 0.70710678118654752f));
            o2 = 0.5f * o2 * (1.0f + erff(o2 * 0.70710678118654752f));
            gb[(size_t)(h * DVV + d) * NTOK + ig]       = o1;
            gb[(size_t)(512 + h * DVV + d) * NTOK + ig] = o2;
        }
    }
}

// ---------------------------------------------------------------------------
// K3: out = BN(Wo @ g + bo, go, bo2).  grid (32, 2, 4), block 256.
// ---------------------------------------------------------------------------
__global__ __launch_bounds__(256) void out_kernel(
    const float* __restrict__ gbuf, const float* __restrict__ Wo,
    const float* __restrict__ bo, const float* __restrict__ go,
    const float* __restrict__ bo2, float* __restrict__ out)
{
    const int b   = blockIdx.z;
    const int n0  = blockIdx.y * 512;
    const int co0 = blockIdx.x * 8;
    const int tid = threadIdx.x;
    const float* gb = gbuf + (size_t)b * 1024 * NTOK;

    float acc[8][2];
    #pragma unroll
    for (int o = 0; o < 8; ++o) { acc[o][0] = 0.0f; acc[o][1] = 0.0f; }

    for (int c = 0; c < 1024; ++c) {
        float g0 = gb[(size_t)c * NTOK + n0 + tid];
        float g1 = gb[(size_t)c * NTOK + n0 + 256 + tid];
        #pragma unroll
        for (int o = 0; o < 8; ++o) {
            float w = Wo[(size_t)(co0 + o) * 1024 + c];
            acc[o][0] = fmaf(w, g0, acc[o][0]);
            acc[o][1] = fmaf(w, g1, acc[o][1]);
        }
    }
    #pragma unroll
    for (int o = 0; o < 8; ++o) {
        int co = co0 + o;
        float v0 = fmaf(acc[o][0] + bo[co], go[co], bo2[co]);
        float v1 = fmaf(acc[o][1] + bo[co], go[co], bo2[co]);
        out[((size_t)b * 256 + co) * NTOK + n0 + tid]       = v0;
        out[((size_t)b * 256 + co) * NTOK + n0 + 256 + tid] = v1;
    }
}

// ---------------------------------------------------------------------------
extern "C" void kernel_launch(void* const* d_in, const int* in_sizes, int n_in,
                              void* d_out, int out_size, void* d_ws, size_t ws_size,
                              hipStream_t stream)
{
    const float* x    = (const float*)d_in[0];
    const float* Wq   = (const float*)d_in[1];
    const float* gq   = (const float*)d_in[2];
    const float* bq   = (const float*)d_in[3];
    const float* Wk   = (const float*)d_in[4];
    const float* gk   = (const float*)d_in[5];
    const float* bk   = (const float*)d_in[6];
    const float* Wv   = (const float*)d_in[7];
    const float* gv   = (const float*)d_in[8];
    const float* bv   = (const float*)d_in[9];
    const float* Wmk  = (const float*)d_in[10];
    const float* gmk  = (const float*)d_in[11];
    const float* bmk  = (const float*)d_in[12];
    const float* pe   = (const float*)d_in[13];
    const float* Wo   = (const float*)d_in[14];
    const float* bo   = (const float*)d_in[15];
    const float* go   = (const float*)d_in[16];
    const float* bo2  = (const float*)d_in[17];
    float* out = (float*)d_out;

    float* w    = (float*)d_ws;
    float* q1   = w;                               // 4*256*1024
    float* kk   = q1 + (size_t)4 * 256 * 1024;     // 4*256*1024
    float* vv   = kk + (size_t)4 * 256 * 1024;     // 4*512*1024
    float* gbuf = vv + (size_t)4 * 512 * 1024;     // 4*1024*1024

    qkv_kernel<<<dim3(128, 4), 256, 0, stream>>>(x, Wq, gq, bq, Wk, gk, bk,
                                                 Wv, gv, bv, q1, kk, vv);
    attn_kernel<<<dim3(32, NHEADS, 4), 256, 0, stream>>>(q1, kk, vv, Wmk, gmk,
                                                         bmk, pe, gbuf);
    out_kernel<<<dim3(32, 2, 4), 256, 0, stream>>>(gbuf, Wo, bo, go, bo2, out);
}

// Round 2
// 264.683 us; speedup vs baseline: 5.1357x; 5.1357x over previous
//
#include <hip/hip_runtime.h>

#define NHEADS 8
#define DKK    32
#define DVV    64
#define NTOK   1024
#define DIM    256

typedef float  f32x4 __attribute__((ext_vector_type(4)));
typedef short  s16x8 __attribute__((ext_vector_type(8)));

__device__ __forceinline__ unsigned short f2bf(float f) {
    unsigned u = __builtin_bit_cast(unsigned, f);
    u += 0x7FFFu + ((u >> 16) & 1u);          // RNE
    return (unsigned short)(u >> 16);
}

// ---------------------------------------------------------------------------
// K0: Wmkb[ch][c] = bf16(gmk[ch] * Wmk[ch][c]).  grid 1024, block 256.
// ---------------------------------------------------------------------------
__global__ __launch_bounds__(256) void wmk_convert(
    const float* __restrict__ Wmk, const float* __restrict__ gmk,
    short* __restrict__ out)
{
    const int sub = threadIdx.x >> 5;            // 0..7
    const int ch  = blockIdx.x * 8 + sub;        // 0..8191
    const int c0  = (threadIdx.x & 31) * 8;
    const float g = gmk[ch];
    const float* src = Wmk + (size_t)ch * DIM + c0;
    float4 x0 = *(const float4*)(src);
    float4 x1 = *(const float4*)(src + 4);
    s16x8 o;
    o[0] = (short)f2bf(g * x0.x); o[1] = (short)f2bf(g * x0.y);
    o[2] = (short)f2bf(g * x0.z); o[3] = (short)f2bf(g * x0.w);
    o[4] = (short)f2bf(g * x1.x); o[5] = (short)f2bf(g * x1.y);
    o[6] = (short)f2bf(g * x1.z); o[7] = (short)f2bf(g * x1.w);
    *(s16x8*)(out + (size_t)ch * DIM + c0) = o;
}

// ---------------------------------------------------------------------------
// K1: q1/k/v = BN(conv1x1(x, W)) -> bf16 workspace.
//   q1t, ktb : token-major [b][1024][256]   (for MFMA A / B fragments)
//   vvb      : conv layout [b][512][1024]
// grid (128, 4), block 256.
// ---------------------------------------------------------------------------
__global__ __launch_bounds__(256) void qkv_kernel(
    const float* __restrict__ x,
    const float* __restrict__ Wq, const float* __restrict__ gq, const float* __restrict__ bq,
    const float* __restrict__ Wk, const float* __restrict__ gk, const float* __restrict__ bk,
    const float* __restrict__ Wv, const float* __restrict__ gv, const float* __restrict__ bv,
    short* __restrict__ q1t, short* __restrict__ ktb, short* __restrict__ vvb)
{
    const int b   = blockIdx.y;
    const int o0  = blockIdx.x * 8;
    const int tid = threadIdx.x;

    const float* W; const float* gg; const float* bb;
    int mode, ol;
    if (o0 < 256)      { mode = 0; ol = o0;       W = Wq + (size_t)ol * DIM; gg = gq + ol; bb = bq + ol; }
    else if (o0 < 512) { mode = 1; ol = o0 - 256; W = Wk + (size_t)ol * DIM; gg = gk + ol; bb = bk + ol; }
    else               { mode = 2; ol = o0 - 512; W = Wv + (size_t)ol * DIM; gg = gv + ol; bb = bv + ol; }

    const float* xb = x + (size_t)b * DIM * NTOK;
    float acc[8][4];
    #pragma unroll
    for (int o = 0; o < 8; ++o)
        #pragma unroll
        for (int r = 0; r < 4; ++r) acc[o][r] = 0.0f;

    for (int c = 0; c < DIM; ++c) {
        float xv[4];
        #pragma unroll
        for (int r = 0; r < 4; ++r) xv[r] = xb[(size_t)c * NTOK + r * 256 + tid];
        #pragma unroll
        for (int o = 0; o < 8; ++o) {
            float w = W[(size_t)o * DIM + c];
            #pragma unroll
            for (int r = 0; r < 4; ++r) acc[o][r] = fmaf(w, xv[r], acc[o][r]);
        }
    }

    if (mode == 2) {
        #pragma unroll
        for (int o = 0; o < 8; ++o) {
            float g = gg[o], be = bb[o];
            #pragma unroll
            for (int r = 0; r < 4; ++r)
                vvb[((size_t)b * 512 + ol + o) * NTOK + r * 256 + tid] =
                    (short)f2bf(fmaf(g, acc[o][r], be));
        }
    } else {
        short* dst = (mode == 0 ? q1t : ktb);
        #pragma unroll
        for (int r = 0; r < 4; ++r) {
            s16x8 pk;
            #pragma unroll
            for (int o = 0; o < 8; ++o)
                pk[o] = (short)f2bf(fmaf(gg[o], acc[o][r], bb[o]));
            *(s16x8*)(dst + ((size_t)b * NTOK + r * 256 + tid) * DIM + ol) = pk;
        }
    }
}

// ---------------------------------------------------------------------------
// K2: fused dual-branch flash attention on MFMA.
// grid (8 i-tiles, 8 h, 4 b), block 512 (8 waves x 16 rows).
// ---------------------------------------------------------------------------
__global__ __launch_bounds__(512, 2) void attn_kernel(
    const short* __restrict__ q1t, const short* __restrict__ ktb,
    const short* __restrict__ vvb, const short* __restrict__ wmkb,
    const float* __restrict__ bmk, const float* __restrict__ pos_emb,
    float* __restrict__ gbuf)
{
    __shared__ __align__(16) short wmks[64 * 264];   // 33,792 B (rows 528B = 33*16)
    __shared__ __align__(16) short ps[8 * 16 * 72];  // 18,432 B (per-wave [16][72])
    __shared__ float pe_s[1024];                     //  4,096 B
    __shared__ float bmk_s[1024];                    //  4,096 B   total 60,416 B

    const int it = blockIdx.x, h = blockIdx.y, b = blockIdx.z;
    const int i0  = it * 128;
    const int tid = threadIdx.x;
    const int w    = tid >> 6;
    const int lane = tid & 63;
    const int l15  = lane & 15;
    const int lhi  = lane >> 4;                      // 0..3

    for (int p = tid; p < 1024; p += 512) {
        pe_s[p]  = pos_emb[p * NHEADS + h] * 5.656854249492380f;  // * sqrt(32)
        bmk_s[p] = bmk[h * NTOK + p];
    }

    // hoisted A fragments (rows i0 + w*16 + l15)
    const short* q1row = q1t + ((size_t)b * NTOK + i0 + w * 16 + l15) * DIM;
    s16x8 a1[8];
    #pragma unroll
    for (int ks = 0; ks < 8; ++ks)
        a1[ks] = *(const s16x8*)(q1row + ks * 32 + lhi * 8);
    s16x8 a2 = *(const s16x8*)(q1row + h * DKK + lhi * 8);

    // per-lane row coords (rows lhi*4+q of the wave tile)
    int ixq[4], iyq[4];
    #pragma unroll
    for (int q = 0; q < 4; ++q) {
        int i = i0 + w * 16 + lhi * 4 + q;
        ixq[q] = i >> 5; iyq[q] = i & 31;
    }

    f32x4 o1[4], o2[4];
    #pragma unroll
    for (int df = 0; df < 4; ++df)
        #pragma unroll
        for (int q = 0; q < 4; ++q) { o1[df][q] = 0.0f; o2[df][q] = 0.0f; }
    float m1[4], l1[4], m2[4], l2[4];
    #pragma unroll
    for (int q = 0; q < 4; ++q) { m1[q] = -INFINITY; l1[q] = 0.f; m2[q] = -INFINITY; l2[q] = 0.f; }

    const short* kbase = ktb  + (size_t)b * NTOK * DIM;
    const short* vbase = vvb  + ((size_t)b * 512 + h * DVV) * NTOK;
    const short* wbase = wmkb + (size_t)h * NTOK * DIM;
    short* psw = ps + w * 16 * 72;
    const float SCALE = 0.17677669529663687f;

    __syncthreads();   // pe_s / bmk_s ready

    for (int jc = 0; jc < 16; ++jc) {
        const int j0 = jc * 64;
        __syncthreads();                       // prior wmks readers done

        #pragma unroll
        for (int s = 0; s < 4; ++s) {          // stage 64x256 bf16 Wmk tile
            int m = tid + s * 512;             // 0..2047
            int row = m >> 5, ch = m & 31;
            s16x8 v = *(const s16x8*)(wbase + (size_t)(j0 + row) * DIM + ch * 8);
            *(s16x8*)(&wmks[row * 264 + ch * 8]) = v;
        }
        __syncthreads();

        // K and V B-fragments straight from global (L2-resident)
        s16x8 b2f[4], vf[2][4];
        #pragma unroll
        for (int df = 0; df < 4; ++df) {
            b2f[df] = *(const s16x8*)(kbase + (size_t)(j0 + df * 16 + l15) * DIM + h * DKK + lhi * 8);
            #pragma unroll
            for (int ks = 0; ks < 2; ++ks)
                vf[ks][df] = *(const s16x8*)(vbase + (size_t)(df * 16 + l15) * NTOK + j0 + ks * 32 + lhi * 8);
        }

        // ---- branch 1: S1 = q1 . Wmk^T  (K=256) ----
        f32x4 s1[4];
        #pragma unroll
        for (int df = 0; df < 4; ++df) {
            f32x4 acc = {0.f, 0.f, 0.f, 0.f};
            #pragma unroll
            for (int ks = 0; ks < 8; ++ks) {
                s16x8 bf = *(const s16x8*)(&wmks[(df * 16 + l15) * 264 + ks * 32 + lhi * 8]);
                acc = __builtin_amdgcn_mfma_f32_16x16x32_bf16(a1[ks], bf, acc, 0, 0, 0);
            }
            s1[df] = acc;
        }
        // bias: bmk + pos_emb[idx]/SCALE
        #pragma unroll
        for (int df = 0; df < 4; ++df) {
            int j  = j0 + df * 16 + l15;
            float bv = bmk_s[j];
            int jx = j >> 5, jy = j & 31;
            #pragma unroll
            for (int q = 0; q < 4; ++q) {
                int dx = ixq[q] - jx; dx = dx < 0 ? -dx : dx;
                int dy = iyq[q] - jy; dy = dy < 0 ? -dy : dy;
                s1[df][q] += bv + pe_s[dx * 32 + dy];
            }
        }
        // online softmax (branch 1) + P1 -> ps
        #pragma unroll
        for (int q = 0; q < 4; ++q) {
            float mx = fmaxf(fmaxf(s1[0][q], s1[1][q]), fmaxf(s1[2][q], s1[3][q]));
            #pragma unroll
            for (int off = 1; off < 16; off <<= 1) mx = fmaxf(mx, __shfl_xor(mx, off, 64));
            float mnew = fmaxf(m1[q], mx);
            float sc = __expf(m1[q] - mnew);
            float rs = 0.f;
            #pragma unroll
            for (int df = 0; df < 4; ++df) {
                float p = __expf(s1[df][q] - mnew);
                rs += p;
                psw[(lhi * 4 + q) * 72 + df * 16 + l15] = (short)f2bf(p);
                o1[df][q] *= sc;
            }
            #pragma unroll
            for (int off = 1; off < 16; off <<= 1) rs += __shfl_xor(rs, off, 64);
            l1[q] = l1[q] * sc + rs;
            m1[q] = mnew;
        }
        // O1 += P1 . V
        {
            s16x8 ap0 = *(const s16x8*)(&psw[l15 * 72 +  0 + lhi * 8]);
            s16x8 ap1 = *(const s16x8*)(&psw[l15 * 72 + 32 + lhi * 8]);
            #pragma unroll
            for (int df = 0; df < 4; ++df) {
                o1[df] = __builtin_amdgcn_mfma_f32_16x16x32_bf16(ap0, vf[0][df], o1[df], 0, 0, 0);
                o1[df] = __builtin_amdgcn_mfma_f32_16x16x32_bf16(ap1, vf[1][df], o1[df], 0, 0, 0);
            }
        }

        // ---- branch 2: S2 = q . k^T * SCALE  (K=32) ----
        f32x4 s2[4];
        #pragma unroll
        for (int df = 0; df < 4; ++df) {
            f32x4 z = {0.f, 0.f, 0.f, 0.f};
            z = __builtin_amdgcn_mfma_f32_16x16x32_bf16(a2, b2f[df], z, 0, 0, 0);
            #pragma unroll
            for (int q = 0; q < 4; ++q) s2[df][q] = z[q] * SCALE;
        }
        #pragma unroll
        for (int q = 0; q < 4; ++q) {
            float mx = fmaxf(fmaxf(s2[0][q], s2[1][q]), fmaxf(s2[2][q], s2[3][q]));
            #pragma unroll
            for (int off = 1; off < 16; off <<= 1) mx = fmaxf(mx, __shfl_xor(mx, off, 64));
            float mnew = fmaxf(m2[q], mx);
            float sc = __expf(m2[q] - mnew);
            float rs = 0.f;
            #pragma unroll
            for (int df = 0; df < 4; ++df) {
                float p = __expf(s2[df][q] - mnew);
                rs += p;
                psw[(lhi * 4 + q) * 72 + df * 16 + l15] = (short)f2bf(p);
                o2[df][q] *= sc;
            }
            #pragma unroll
            for (int off = 1; off < 16; off <<= 1) rs += __shfl_xor(rs, off, 64);
            l2[q] = l2[q] * sc + rs;
            m2[q] = mnew;
        }
        {
            s16x8 ap0 = *(const s16x8*)(&psw[l15 * 72 +  0 + lhi * 8]);
            s16x8 ap1 = *(const s16x8*)(&psw[l15 * 72 + 32 + lhi * 8]);
            #pragma unroll
            for (int df = 0; df < 4; ++df) {
                o2[df] = __builtin_amdgcn_mfma_f32_16x16x32_bf16(ap0, vf[0][df], o2[df], 0, 0, 0);
                o2[df] = __builtin_amdgcn_mfma_f32_16x16x32_bf16(ap1, vf[1][df], o2[df], 0, 0, 0);
            }
        }
    }

    // ---- epilogue: normalize, GELU, LDS-transpose, coalesced f32 store ----
    float* osw = (float*)wmks;                // [128][65] f32 = 33,280 B overlay
    #pragma unroll
    for (int pass = 0; pass < 2; ++pass) {
        __syncthreads();
        const int chbase = pass == 0 ? h * DVV : 512 + h * DVV;
        #pragma unroll
        for (int df = 0; df < 4; ++df)
            #pragma unroll
            for (int q = 0; q < 4; ++q) {
                float v = (pass == 0 ? o1[df][q] / l1[q] : o2[df][q] / l2[q]);
                v = 0.5f * v * (1.0f + erff(v * 0.70710678118654752f));
                osw[(w * 16 + lhi * 4 + q) * 65 + df * 16 + l15] = v;
            }
        __syncthreads();
        #pragma unroll
        for (int s = 0; s < 4; ++s) {
            int m = tid + s * 512;            // 0..2047 : 64 ch x 32 float4
            int ch = m >> 5, t4 = (m & 31) * 4;
            float4 v;
            v.x = osw[(t4 + 0) * 65 + ch];
            v.y = osw[(t4 + 1) * 65 + ch];
            v.z = osw[(t4 + 2) * 65 + ch];
            v.w = osw[(t4 + 3) * 65 + ch];
            *(float4*)(gbuf + ((size_t)b * 1024 + chbase + ch) * NTOK + i0 + t4) = v;
        }
    }
}

// ---------------------------------------------------------------------------
// K3: out = BN(Wo @ g + bo).  grid (32, 2, 4), block 256.  (unchanged)
// ---------------------------------------------------------------------------
__global__ __launch_bounds__(256) void out_kernel(
    const float* __restrict__ gbuf, const float* __restrict__ Wo,
    const float* __restrict__ bo, const float* __restrict__ go,
    const float* __restrict__ bo2, float* __restrict__ out)
{
    const int b   = blockIdx.z;
    const int n0  = blockIdx.y * 512;
    const int co0 = blockIdx.x * 8;
    const int tid = threadIdx.x;
    const float* gb = gbuf + (size_t)b * 1024 * NTOK;

    float acc[8][2];
    #pragma unroll
    for (int o = 0; o < 8; ++o) { acc[o][0] = 0.0f; acc[o][1] = 0.0f; }

    for (int c = 0; c < 1024; ++c) {
        float g0 = gb[(size_t)c * NTOK + n0 + tid];
        float g1 = gb[(size_t)c * NTOK + n0 + 256 + tid];
        #pragma unroll
        for (int o = 0; o < 8; ++o) {
            float w = Wo[(size_t)(co0 + o) * 1024 + c];
            acc[o][0] = fmaf(w, g0, acc[o][0]);
            acc[o][1] = fmaf(w, g1, acc[o][1]);
        }
    }
    #pragma unroll
    for (int o = 0; o < 8; ++o) {
        int co = co0 + o;
        float v0 = fmaf(acc[o][0] + bo[co], go[co], bo2[co]);
        float v1 = fmaf(acc[o][1] + bo[co], go[co], bo2[co]);
        out[((size_t)b * 256 + co) * NTOK + n0 + tid]       = v0;
        out[((size_t)b * 256 + co) * NTOK + n0 + 256 + tid] = v1;
    }
}

// ---------------------------------------------------------------------------
extern "C" void kernel_launch(void* const* d_in, const int* in_sizes, int n_in,
                              void* d_out, int out_size, void* d_ws, size_t ws_size,
                              hipStream_t stream)
{
    const float* x    = (const float*)d_in[0];
    const float* Wq   = (const float*)d_in[1];
    const float* gq   = (const float*)d_in[2];
    const float* bq   = (const float*)d_in[3];
    const float* Wk   = (const float*)d_in[4];
    const float* gk   = (const float*)d_in[5];
    const float* bk   = (const float*)d_in[6];
    const float* Wv   = (const float*)d_in[7];
    const float* gv   = (const float*)d_in[8];
    const float* bv   = (const float*)d_in[9];
    const float* Wmk  = (const float*)d_in[10];
    const float* gmk  = (const float*)d_in[11];
    const float* bmk  = (const float*)d_in[12];
    const float* pe   = (const float*)d_in[13];
    const float* Wo   = (const float*)d_in[14];
    const float* bo   = (const float*)d_in[15];
    const float* go   = (const float*)d_in[16];
    const float* bo2  = (const float*)d_in[17];
    float* out = (float*)d_out;

    char* base = (char*)d_ws;
    short* q1t  = (short*)base;                       // 2 MB
    short* ktb  = (short*)(base + (2u  << 20));       // 2 MB
    short* vvb  = (short*)(base + (4u  << 20));       // 4 MB
    short* wmkb = (short*)(base + (8u  << 20));       // 4 MB
    float* gbuf = (float*)(base + (12u << 20));       // 16 MB

    wmk_convert<<<dim3(1024), 256, 0, stream>>>(Wmk, gmk, wmkb);
    qkv_kernel<<<dim3(128, 4), 256, 0, stream>>>(x, Wq, gq, bq, Wk, gk, bk,
                                                 Wv, gv, bv, q1t, ktb, vvb);
    attn_kernel<<<dim3(8, NHEADS, 4), 512, 0, stream>>>(q1t, ktb, vvb, wmkb,
                                                        bmk, pe, gbuf);
    out_kernel<<<dim3(32, 2, 4), 256, 0, stream>>>(gbuf, Wo, bo, go, bo2, out);
}

// Round 3
// 143.136 us; speedup vs baseline: 9.4967x; 1.8492x over previous
//
#include <hip/hip_runtime.h>

#define NHEADS 8
#define DKK    32
#define DVV    64
#define NTOK   1024
#define DIM    256

typedef float  f32x4 __attribute__((ext_vector_type(4)));
typedef short  s16x4 __attribute__((ext_vector_type(4)));
typedef short  s16x8 __attribute__((ext_vector_type(8)));

__device__ __forceinline__ unsigned short f2bf(float f) {
    unsigned u = __builtin_bit_cast(unsigned, f);
    u += 0x7FFFu + ((u >> 16) & 1u);          // RNE
    return (unsigned short)(u >> 16);
}

// ---------------------------------------------------------------------------
// C0: x [b][256][1024] f32  ->  xbt [b*1024+tok][256] bf16 (token-major)
// grid (16 n-tiles, 4 c-tiles, 4 b), block 256.
// ---------------------------------------------------------------------------
__global__ __launch_bounds__(256) void conv_x(
    const float* __restrict__ x, short* __restrict__ xbt)
{
    __shared__ short tl[64 * 72];
    const int n0 = blockIdx.x * 64, c0 = blockIdx.y * 64, b = blockIdx.z;
    const int tid = threadIdx.x;
    #pragma unroll
    for (int s = 0; s < 16; ++s) {
        int id = tid + s * 256;               // 0..4095
        int cc = id >> 6, nn = id & 63;
        tl[nn * 72 + cc] = (short)f2bf(x[(size_t)b * 262144 + (size_t)(c0 + cc) * 1024 + n0 + nn]);
    }
    __syncthreads();
    #pragma unroll
    for (int s = 0; s < 2; ++s) {
        int id = tid + s * 256;               // 0..511
        int nn = id >> 3, c8 = id & 7;
        *(s16x8*)(xbt + ((size_t)b * 1024 + n0 + nn) * 256 + c0 + c8 * 8) =
            *(const s16x8*)&tl[nn * 72 + c8 * 8];
    }
}

// ---------------------------------------------------------------------------
// C1: wqkvb[1024][256] bf16 = gamma-folded {Wq|Wk|Wv}.  grid 128, block 256.
// ---------------------------------------------------------------------------
__global__ __launch_bounds__(256) void conv_wqkv(
    const float* __restrict__ Wq, const float* __restrict__ gq,
    const float* __restrict__ Wk, const float* __restrict__ gk,
    const float* __restrict__ Wv, const float* __restrict__ gv,
    short* __restrict__ wqkvb)
{
    const int sub = threadIdx.x >> 5;
    const int row = blockIdx.x * 8 + sub;     // 0..1023
    const int c0  = (threadIdx.x & 31) * 8;
    float g; const float* src;
    if (row < 256)      { g = gq[row];       src = Wq + (size_t)row * DIM; }
    else if (row < 512) { g = gk[row - 256]; src = Wk + (size_t)(row - 256) * DIM; }
    else                { g = gv[row - 512]; src = Wv + (size_t)(row - 512) * DIM; }
    float4 x0 = *(const float4*)(src + c0);
    float4 x1 = *(const float4*)(src + c0 + 4);
    s16x8 o;
    o[0] = (short)f2bf(g * x0.x); o[1] = (short)f2bf(g * x0.y);
    o[2] = (short)f2bf(g * x0.z); o[3] = (short)f2bf(g * x0.w);
    o[4] = (short)f2bf(g * x1.x); o[5] = (short)f2bf(g * x1.y);
    o[6] = (short)f2bf(g * x1.z); o[7] = (short)f2bf(g * x1.w);
    *(s16x8*)(wqkvb + (size_t)row * DIM + c0) = o;
}

// ---------------------------------------------------------------------------
// C2: wmkb[8192][256] bf16 = gmk-folded Wmk.  grid 1024, block 256.
// ---------------------------------------------------------------------------
__global__ __launch_bounds__(256) void wmk_convert(
    const float* __restrict__ Wmk, const float* __restrict__ gmk,
    short* __restrict__ out)
{
    const int sub = threadIdx.x >> 5;
    const int ch  = blockIdx.x * 8 + sub;
    const int c0  = (threadIdx.x & 31) * 8;
    const float g = gmk[ch];
    const float* src = Wmk + (size_t)ch * DIM + c0;
    float4 x0 = *(const float4*)(src);
    float4 x1 = *(const float4*)(src + 4);
    s16x8 o;
    o[0] = (short)f2bf(g * x0.x); o[1] = (short)f2bf(g * x0.y);
    o[2] = (short)f2bf(g * x0.z); o[3] = (short)f2bf(g * x0.w);
    o[4] = (short)f2bf(g * x1.x); o[5] = (short)f2bf(g * x1.y);
    o[6] = (short)f2bf(g * x1.z); o[7] = (short)f2bf(g * x1.w);
    *(s16x8*)(out + (size_t)ch * DIM + c0) = o;
}

// ---------------------------------------------------------------------------
// C3: wob[256][1024] bf16 = Wo.  grid 32, block 256.
// ---------------------------------------------------------------------------
__global__ __launch_bounds__(256) void conv_wo(
    const float* __restrict__ Wo, short* __restrict__ wob)
{
    const int sub = threadIdx.x >> 5;
    const int row = blockIdx.x * 8 + sub;     // 0..255
    const int l   = threadIdx.x & 31;
    #pragma unroll
    for (int u = 0; u < 4; ++u) {
        int c = l * 8 + u * 256;
        const float* src = Wo + (size_t)row * 1024 + c;
        float4 x0 = *(const float4*)(src);
        float4 x1 = *(const float4*)(src + 4);
        s16x8 o;
        o[0] = (short)f2bf(x0.x); o[1] = (short)f2bf(x0.y);
        o[2] = (short)f2bf(x0.z); o[3] = (short)f2bf(x0.w);
        o[4] = (short)f2bf(x1.x); o[5] = (short)f2bf(x1.y);
        o[6] = (short)f2bf(x1.z); o[7] = (short)f2bf(x1.w);
        *(s16x8*)(wob + (size_t)row * 1024 + c) = o;
    }
}

// ---------------------------------------------------------------------------
// K1: qkv GEMM on MFMA.  M=1024 ch, N=4096 tok, K=256.
// grid (64 tok-tiles, 8 ch-tiles), block 256 (4 waves, 2x2), tile 128ch x 64tok.
// ch 0..511 -> qk_t [4096][512] token-major (LDS transpose);
// ch 512..1023 -> vvb [512][4096] conv layout.
// ---------------------------------------------------------------------------
__global__ __launch_bounds__(256) void qkv_mfma(
    const short* __restrict__ wqkvb, const short* __restrict__ xbt,
    const float* __restrict__ bq, const float* __restrict__ bk,
    const float* __restrict__ bv,
    short* __restrict__ qk_t, short* __restrict__ vvb)
{
    __shared__ __align__(16) short tlds[64 * 136];   // 17,408 B

    const int t0 = blockIdx.x * 64;
    const int c0 = blockIdx.y * 128;
    const int tid  = threadIdx.x;
    const int w    = tid >> 6, lane = tid & 63;
    const int l15  = lane & 15, lhi = lane >> 4;
    const int wr = w >> 1, wc = w & 1;
    const int cob = c0 + wr * 64;
    const int tob = t0 + wc * 32;

    f32x4 acc[4][2];
    #pragma unroll
    for (int mf = 0; mf < 4; ++mf)
        #pragma unroll
        for (int nf = 0; nf < 2; ++nf) acc[mf][nf] = (f32x4){0.f, 0.f, 0.f, 0.f};

    #pragma unroll
    for (int ks = 0; ks < 8; ++ks) {
        s16x8 af[4], bf[2];
        #pragma unroll
        for (int mf = 0; mf < 4; ++mf)
            af[mf] = *(const s16x8*)(wqkvb + (size_t)(cob + mf * 16 + l15) * DIM + ks * 32 + lhi * 8);
        #pragma unroll
        for (int nf = 0; nf < 2; ++nf)
            bf[nf] = *(const s16x8*)(xbt + (size_t)(tob + nf * 16 + l15) * DIM + ks * 32 + lhi * 8);
        #pragma unroll
        for (int mf = 0; mf < 4; ++mf)
            #pragma unroll
            for (int nf = 0; nf < 2; ++nf)
                acc[mf][nf] = __builtin_amdgcn_mfma_f32_16x16x32_bf16(af[mf], bf[nf], acc[mf][nf], 0, 0, 0);
    }

    // per-(mf,q) channel bias
    float bias[4][4];
    #pragma unroll
    for (int mf = 0; mf < 4; ++mf)
        #pragma unroll
        for (int q = 0; q < 4; ++q) {
            int ch = cob + mf * 16 + lhi * 4 + q;
            bias[mf][q] = (ch < 256) ? bq[ch] : (ch < 512) ? bk[ch - 256] : bv[ch - 512];
        }

    if (c0 < 512) {
        // token-major via LDS transpose
        #pragma unroll
        for (int mf = 0; mf < 4; ++mf)
            #pragma unroll
            for (int nf = 0; nf < 2; ++nf) {
                s16x4 pk;
                #pragma unroll
                for (int q = 0; q < 4; ++q)
                    pk[q] = (short)f2bf(acc[mf][nf][q] + bias[mf][q]);
                int tokl = wc * 32 + nf * 16 + l15;
                int chl  = wr * 64 + mf * 16 + lhi * 4;
                *(s16x4*)&tlds[tokl * 136 + chl] = pk;
            }
        __syncthreads();
        #pragma unroll
        for (int s = 0; s < 4; ++s) {
            int id = tid + s * 256;            // 0..1023 : 64 tok x 16 ch-chunks
            int tok = id >> 4, c8 = id & 15;
            *(s16x8*)(qk_t + (size_t)(t0 + tok) * 512 + c0 + c8 * 8) =
                *(const s16x8*)&tlds[tok * 136 + c8 * 8];
        }
    } else {
        // conv layout, coalesced-in-token scalar stores
        #pragma unroll
        for (int mf = 0; mf < 4; ++mf)
            #pragma unroll
            for (int nf = 0; nf < 2; ++nf) {
                int gt = tob + nf * 16 + l15;
                #pragma unroll
                for (int q = 0; q < 4; ++q) {
                    int vch = cob + mf * 16 + lhi * 4 + q - 512;
                    vvb[(size_t)vch * 4096 + gt] = (short)f2bf(acc[mf][nf][q] + bias[mf][q]);
                }
            }
    }
}

// ---------------------------------------------------------------------------
// K2: fused dual-branch flash attention on MFMA.
// grid (8 i-tiles, 8 h, 4 b), block 512 (8 waves x 16 rows).
// Writes gbuf bf16 token-major [4096][1024] (out1 ch h*64.., out2 512+h*64..).
// ---------------------------------------------------------------------------
__global__ __launch_bounds__(512, 2) void attn_kernel(
    const short* __restrict__ qk_t, const short* __restrict__ vvb,
    const short* __restrict__ wmkb, const float* __restrict__ bmk,
    const float* __restrict__ pos_emb, short* __restrict__ gbuf)
{
    __shared__ __align__(16) short wmks[64 * 264];   // 33,792 B
    __shared__ __align__(16) short ps[8 * 16 * 72];  // 18,432 B
    __shared__ float pe_s[1024];
    __shared__ float bmk_s[1024];                    // total 60,416 B

    const int it = blockIdx.x, h = blockIdx.y, b = blockIdx.z;
    const int i0  = it * 128;
    const int tid = threadIdx.x;
    const int w    = tid >> 6;
    const int lane = tid & 63;
    const int l15  = lane & 15;
    const int lhi  = lane >> 4;

    for (int p = tid; p < 1024; p += 512) {
        pe_s[p]  = pos_emb[p * NHEADS + h] * 5.656854249492380f;
        bmk_s[p] = bmk[h * NTOK + p];
    }

    const short* q1row = qk_t + ((size_t)b * NTOK + i0 + w * 16 + l15) * 512;
    s16x8 a1[8];
    #pragma unroll
    for (int ks = 0; ks < 8; ++ks)
        a1[ks] = *(const s16x8*)(q1row + ks * 32 + lhi * 8);
    s16x8 a2 = *(const s16x8*)(q1row + h * DKK + lhi * 8);

    int ixq[4], iyq[4];
    #pragma unroll
    for (int q = 0; q < 4; ++q) {
        int i = i0 + w * 16 + lhi * 4 + q;
        ixq[q] = i >> 5; iyq[q] = i & 31;
    }

    f32x4 o1[4], o2[4];
    #pragma unroll
    for (int df = 0; df < 4; ++df)
        #pragma unroll
        for (int q = 0; q < 4; ++q) { o1[df][q] = 0.0f; o2[df][q] = 0.0f; }
    float m1[4], l1[4], m2[4], l2[4];
    #pragma unroll
    for (int q = 0; q < 4; ++q) { m1[q] = -INFINITY; l1[q] = 0.f; m2[q] = -INFINITY; l2[q] = 0.f; }

    const short* kbase = qk_t + (size_t)b * NTOK * 512 + 256 + h * DKK;
    const short* vbase = vvb + (size_t)(h * DVV) * 4096 + b * NTOK;
    const short* wbase = wmkb + (size_t)h * NTOK * DIM;
    short* psw = ps + w * 16 * 72;
    const float SCALE = 0.17677669529663687f;

    __syncthreads();

    for (int jc = 0; jc < 16; ++jc) {
        const int j0 = jc * 64;
        __syncthreads();

        #pragma unroll
        for (int s = 0; s < 4; ++s) {
            int m = tid + s * 512;
            int row = m >> 5, ch = m & 31;
            s16x8 v = *(const s16x8*)(wbase + (size_t)(j0 + row) * DIM + ch * 8);
            *(s16x8*)(&wmks[row * 264 + ch * 8]) = v;
        }
        __syncthreads();

        s16x8 b2f[4], vf[2][4];
        #pragma unroll
        for (int df = 0; df < 4; ++df) {
            b2f[df] = *(const s16x8*)(kbase + (size_t)(j0 + df * 16 + l15) * 512 + lhi * 8);
            #pragma unroll
            for (int ks = 0; ks < 2; ++ks)
                vf[ks][df] = *(const s16x8*)(vbase + (size_t)(df * 16 + l15) * 4096 + j0 + ks * 32 + lhi * 8);
        }

        // ---- branch 1 ----
        f32x4 s1[4];
        #pragma unroll
        for (int df = 0; df < 4; ++df) {
            f32x4 acc = {0.f, 0.f, 0.f, 0.f};
            #pragma unroll
            for (int ks = 0; ks < 8; ++ks) {
                s16x8 bfr = *(const s16x8*)(&wmks[(df * 16 + l15) * 264 + ks * 32 + lhi * 8]);
                acc = __builtin_amdgcn_mfma_f32_16x16x32_bf16(a1[ks], bfr, acc, 0, 0, 0);
            }
            s1[df] = acc;
        }
        #pragma unroll
        for (int df = 0; df < 4; ++df) {
            int j  = j0 + df * 16 + l15;
            float bv = bmk_s[j];
            int jx = j >> 5, jy = j & 31;
            #pragma unroll
            for (int q = 0; q < 4; ++q) {
                int dx = ixq[q] - jx; dx = dx < 0 ? -dx : dx;
                int dy = iyq[q] - jy; dy = dy < 0 ? -dy : dy;
                s1[df][q] += bv + pe_s[dx * 32 + dy];
            }
        }
        #pragma unroll
        for (int q = 0; q < 4; ++q) {
            float mx = fmaxf(fmaxf(s1[0][q], s1[1][q]), fmaxf(s1[2][q], s1[3][q]));
            #pragma unroll
            for (int off = 1; off < 16; off <<= 1) mx = fmaxf(mx, __shfl_xor(mx, off, 64));
            float mnew = fmaxf(m1[q], mx);
            float sc = __expf(m1[q] - mnew);
            float rs = 0.f;
            #pragma unroll
            for (int df = 0; df < 4; ++df) {
                float p = __expf(s1[df][q] - mnew);
                rs += p;
                psw[(lhi * 4 + q) * 72 + df * 16 + l15] = (short)f2bf(p);
                o1[df][q] *= sc;
            }
            #pragma unroll
            for (int off = 1; off < 16; off <<= 1) rs += __shfl_xor(rs, off, 64);
            l1[q] = l1[q] * sc + rs;
            m1[q] = mnew;
        }
        {
            s16x8 ap0 = *(const s16x8*)(&psw[l15 * 72 +  0 + lhi * 8]);
            s16x8 ap1 = *(const s16x8*)(&psw[l15 * 72 + 32 + lhi * 8]);
            #pragma unroll
            for (int df = 0; df < 4; ++df) {
                o1[df] = __builtin_amdgcn_mfma_f32_16x16x32_bf16(ap0, vf[0][df], o1[df], 0, 0, 0);
                o1[df] = __builtin_amdgcn_mfma_f32_16x16x32_bf16(ap1, vf[1][df], o1[df], 0, 0, 0);
            }
        }

        // ---- branch 2 ----
        f32x4 s2[4];
        #pragma unroll
        for (int df = 0; df < 4; ++df) {
            f32x4 z = {0.f, 0.f, 0.f, 0.f};
            z = __builtin_amdgcn_mfma_f32_16x16x32_bf16(a2, b2f[df], z, 0, 0, 0);
            #pragma unroll
            for (int q = 0; q < 4; ++q) s2[df][q] = z[q] * SCALE;
        }
        #pragma unroll
        for (int q = 0; q < 4; ++q) {
            float mx = fmaxf(fmaxf(s2[0][q], s2[1][q]), fmaxf(s2[2][q], s2[3][q]));
            #pragma unroll
            for (int off = 1; off < 16; off <<= 1) mx = fmaxf(mx, __shfl_xor(mx, off, 64));
            float mnew = fmaxf(m2[q], mx);
            float sc = __expf(m2[q] - mnew);
            float rs = 0.f;
            #pragma unroll
            for (int df = 0; df < 4; ++df) {
                float p = __expf(s2[df][q] - mnew);
                rs += p;
                psw[(lhi * 4 + q) * 72 + df * 16 + l15] = (short)f2bf(p);
                o2[df][q] *= sc;
            }
            #pragma unroll
            for (int off = 1; off < 16; off <<= 1) rs += __shfl_xor(rs, off, 64);
            l2[q] = l2[q] * sc + rs;
            m2[q] = mnew;
        }
        {
            s16x8 ap0 = *(const s16x8*)(&psw[l15 * 72 +  0 + lhi * 8]);
            s16x8 ap1 = *(const s16x8*)(&psw[l15 * 72 + 32 + lhi * 8]);
            #pragma unroll
            for (int df = 0; df < 4; ++df) {
                o2[df] = __builtin_amdgcn_mfma_f32_16x16x32_bf16(ap0, vf[0][df], o2[df], 0, 0, 0);
                o2[df] = __builtin_amdgcn_mfma_f32_16x16x32_bf16(ap1, vf[1][df], o2[df], 0, 0, 0);
            }
        }
    }

    // ---- epilogue: normalize, GELU, LDS-transpose, bf16 token-major store ----
    short* osw = wmks;                 // overlay: [128][72] shorts
    #pragma unroll
    for (int pass = 0; pass < 2; ++pass) {
        __syncthreads();
        const int chbase = pass == 0 ? h * DVV : 512 + h * DVV;
        #pragma unroll
        for (int df = 0; df < 4; ++df)
            #pragma unroll
            for (int q = 0; q < 4; ++q) {
                float v = (pass == 0 ? o1[df][q] / l1[q] : o2[df][q] / l2[q]);
                v = 0.5f * v * (1.0f + erff(v * 0.70710678118654752f));
                osw[(w * 16 + lhi * 4 + q) * 72 + df * 16 + l15] = (short)f2bf(v);
            }
        __syncthreads();
        #pragma unroll
        for (int s = 0; s < 2; ++s) {
            int id = tid + s * 512;    // 0..1023 : 128 tok x 8 ch-chunks
            int tok = id >> 3, c8 = id & 7;
            *(s16x8*)(gbuf + ((size_t)b * NTOK + i0 + tok) * 1024 + chbase + c8 * 8) =
                *(const s16x8*)&osw[tok * 72 + c8 * 8];
        }
    }
}

// ---------------------------------------------------------------------------
// K3: out GEMM on MFMA.  M=256 co, N=4096 tok, K=1024.
// grid (64 tok-tiles, 4 co-tiles), block 256 (4 waves 2x2), tile 64x64.
// ---------------------------------------------------------------------------
__global__ __launch_bounds__(256) void out_mfma(
    const short* __restrict__ wob, const short* __restrict__ gbuf,
    const float* __restrict__ bo, const float* __restrict__ go,
    const float* __restrict__ bo2, float* __restrict__ out)
{
    const int t0 = blockIdx.x * 64;
    const int c0 = blockIdx.y * 64;
    const int tid  = threadIdx.x;
    const int w    = tid >> 6, lane = tid & 63;
    const int l15  = lane & 15, lhi = lane >> 4;
    const int wr = w >> 1, wc = w & 1;
    const int cob = c0 + wr * 32;
    const int tob = t0 + wc * 32;

    f32x4 acc[2][2];
    #pragma unroll
    for (int mf = 0; mf < 2; ++mf)
        #pragma unroll
        for (int nf = 0; nf < 2; ++nf) acc[mf][nf] = (f32x4){0.f, 0.f, 0.f, 0.f};

    #pragma unroll 4
    for (int ks = 0; ks < 32; ++ks) {
        s16x8 af[2], bf[2];
        #pragma unroll
        for (int mf = 0; mf < 2; ++mf)
            af[mf] = *(const s16x8*)(wob + (size_t)(cob + mf * 16 + l15) * 1024 + ks * 32 + lhi * 8);
        #pragma unroll
        for (int nf = 0; nf < 2; ++nf)
            bf[nf] = *(const s16x8*)(gbuf + (size_t)(tob + nf * 16 + l15) * 1024 + ks * 32 + lhi * 8);
        #pragma unroll
        for (int mf = 0; mf < 2; ++mf)
            #pragma unroll
            for (int nf = 0; nf < 2; ++nf)
                acc[mf][nf] = __builtin_amdgcn_mfma_f32_16x16x32_bf16(af[mf], bf[nf], acc[mf][nf], 0, 0, 0);
    }

    #pragma unroll
    for (int mf = 0; mf < 2; ++mf) {
        #pragma unroll
        for (int q = 0; q < 4; ++q) {
            int co = cob + mf * 16 + lhi * 4 + q;
            float bov = bo[co], gov = go[co], bo2v = bo2[co];
            #pragma unroll
            for (int nf = 0; nf < 2; ++nf) {
                int gt = tob + nf * 16 + l15;
                int bb = gt >> 10, n = gt & 1023;
                out[(size_t)bb * 262144 + (size_t)co * 1024 + n] =
                    fmaf(acc[mf][nf][q] + bov, gov, bo2v);
            }
        }
    }
}

// ---------------------------------------------------------------------------
extern "C" void kernel_launch(void* const* d_in, const int* in_sizes, int n_in,
                              void* d_out, int out_size, void* d_ws, size_t ws_size,
                              hipStream_t stream)
{
    const float* x    = (const float*)d_in[0];
    const float* Wq   = (const float*)d_in[1];
    const float* gq   = (const float*)d_in[2];
    const float* bq   = (const float*)d_in[3];
    const float* Wk   = (const float*)d_in[4];
    const float* gk   = (const float*)d_in[5];
    const float* bk   = (const float*)d_in[6];
    const float* Wv   = (const float*)d_in[7];
    const float* gv   = (const float*)d_in[8];
    const float* bv   = (const float*)d_in[9];
    const float* Wmk  = (const float*)d_in[10];
    const float* gmk  = (const float*)d_in[11];
    const float* bmk  = (const float*)d_in[12];
    const float* pe   = (const float*)d_in[13];
    const float* Wo   = (const float*)d_in[14];
    const float* bo   = (const float*)d_in[15];
    const float* go   = (const float*)d_in[16];
    const float* bo2  = (const float*)d_in[17];
    float* out = (float*)d_out;

    char* base = (char*)d_ws;
    short* xbt   = (short*)(base);                     //  2.0 MB
    short* wqkvb = (short*)(base + (2u  << 20));       //  0.5 MB
    short* wmkb  = (short*)(base + (3u  << 20));       //  4.0 MB
    short* wob   = (short*)(base + (7u  << 20));       //  0.5 MB
    short* qk_t  = (short*)(base + (8u  << 20));       //  4.0 MB
    short* vvb   = (short*)(base + (12u << 20));       //  4.0 MB
    short* gbuf  = (short*)(base + (16u << 20));       //  8.0 MB

    conv_x<<<dim3(16, 4, 4), 256, 0, stream>>>(x, xbt);
    conv_wqkv<<<dim3(128), 256, 0, stream>>>(Wq, gq, Wk, gk, Wv, gv, wqkvb);
    wmk_convert<<<dim3(1024), 256, 0, stream>>>(Wmk, gmk, wmkb);
    conv_wo<<<dim3(32), 256, 0, stream>>>(Wo, wob);
    qkv_mfma<<<dim3(64, 8), 256, 0, stream>>>(wqkvb, xbt, bq, bk, bv, qk_t, vvb);
    attn_kernel<<<dim3(8, NHEADS, 4), 512, 0, stream>>>(qk_t, vvb, wmkb, bmk, pe, gbuf);
    out_mfma<<<dim3(64, 4), 256, 0, stream>>>(wob, gbuf, bo, go, bo2, out);
}